// Round 1
// baseline (338.736 us; speedup 1.0000x reference)
//
#include <hip/hip_runtime.h>
#include <math.h>

typedef __attribute__((ext_vector_type(4))) float f32x4;
typedef __attribute__((ext_vector_type(8))) short bf16x8;
typedef __attribute__((ext_vector_type(4))) unsigned int uint4v;

#define LOG2E 1.4426950408889634f

static __device__ __forceinline__ unsigned short f2bf(float f) {
  union { float f; unsigned int i; } u; u.f = f;
  unsigned int r = u.i + 0x7fffu + ((u.i >> 16) & 1u);   // round-nearest-even
  return (unsigned short)(r >> 16);
}

// ---------------- kernel 0: transpose first-layer weights [32][256] -> [256][32]
__global__ __launch_bounds__(256) void k_wprep(const float* __restrict__ w1a,
                                               const float* __restrict__ w2a,
                                               float* __restrict__ w1aT,
                                               float* __restrict__ w2aT) {
  int i = blockIdx.x * 256 + threadIdx.x;   // 8192 elements
  if (i < 32 * 256) {
    int o = i >> 8, c = i & 255;
    w1aT[c * 32 + o] = w1a[i];
    w2aT[c * 32 + o] = w2a[i];
  }
}

// ---------------- kernel 1: q/k projections (fp32 math) + F->bf16
// blocks 0..63: q path (also writes Fbf); blocks 64..127: k path.
__global__ __launch_bounds__(256) void k_qk(
    const float* __restrict__ F,
    const float* __restrict__ w1aT, const float* __restrict__ b1a,
    const float* __restrict__ w1b,  const float* __restrict__ b1b,
    const float* __restrict__ w2aT, const float* __restrict__ b2a,
    const float* __restrict__ w2b,  const float* __restrict__ b2b,
    unsigned short* __restrict__ Fbf,
    unsigned short* __restrict__ qT,
    unsigned short* __restrict__ kT) {
  const int p = blockIdx.x >> 6;                       // 0=q, 1=k (wave-uniform)
  const int nflat = ((blockIdx.x & 63) << 8) | threadIdx.x;  // 0..16383 = b*4096+n
  const int b = nflat >> 12, n = nflat & 4095;
  const float* __restrict__ wA = p ? w2aT : w1aT;
  const float* __restrict__ bA = p ? b2a : b1a;
  const float* __restrict__ wB = p ? w2b : w1b;
  const float* __restrict__ bB = p ? b2b : b1b;
  const float* Fb = F + ((size_t)b * 256) * 4096 + n;

  float h[32];
#pragma unroll
  for (int o = 0; o < 32; ++o) h[o] = 0.f;

  for (int c = 0; c < 256; ++c) {
    float f = Fb[(size_t)c * 4096];                    // coalesced (consecutive n)
    if (p == 0) Fbf[((size_t)b * 256 + c) * 4096 + n] = f2bf(f);
#pragma unroll
    for (int o = 0; o < 32; ++o) h[o] += wA[c * 32 + o] * f;  // uniform -> s_load
  }
#pragma unroll
  for (int o = 0; o < 32; ++o) h[o] = fmaxf(h[o] + bA[o], 0.f);

  unsigned int pack[16];
#pragma unroll
  for (int o2 = 0; o2 < 32; o2 += 2) {
    float s0 = bB[o2], s1 = bB[o2 + 1];
#pragma unroll
    for (int o = 0; o < 32; ++o) {
      s0 += wB[o2 * 32 + o] * h[o];
      s1 += wB[(o2 + 1) * 32 + o] * h[o];
    }
    if (p == 0) { s0 *= LOG2E; s1 *= LOG2E; }          // q in exp2 domain
    pack[o2 >> 1] = (unsigned int)f2bf(s0) | ((unsigned int)f2bf(s1) << 16);
  }
  unsigned short* dst = (p ? kT : qT) + (size_t)nflat * 32;  // [b][n][32]
  uint4v* d4 = (uint4v*)dst;
#pragma unroll
  for (int i = 0; i < 4; ++i) {
    uint4v v = {pack[4 * i], pack[4 * i + 1], pack[4 * i + 2], pack[4 * i + 3]};
    d4[i] = v;
  }
}

// ---------------- kernel 2: flash attention + residual
// 4 waves/block, each wave owns 16 query rows (QT=64). m-tiles of 64.
// mfma_f32_16x16x32_bf16 lane mapping assumed:
//   A: row = lane&15, k = (lane>>4)*8 + j     (8 contiguous bf16 per lane)
//   B: col = lane&15, k = (lane>>4)*8 + j
//   D: col = lane&15, row = (lane>>4)*4 + reg
__global__ __launch_bounds__(256, 1) void k_attn(
    const unsigned short* __restrict__ qT,
    const unsigned short* __restrict__ kT,
    const unsigned short* __restrict__ Fbf,
    const float* __restrict__ F,
    float* __restrict__ out) {
  __shared__ unsigned short Vt[256][72];   // V tile [c][m], +8 pad (2-way = free)
  __shared__ unsigned short Pb[4][16][72]; // per-wave P round-trip buffer

  const int tid = threadIdx.x;
  const int w = tid >> 6;
  const int lane = tid & 63;
  const int lo = lane & 15;
  const int hi = lane >> 4;

  // bijective XCD swizzle: 256 wgs / 8 XCDs -> contiguous 32-chunk per XCD
  const int bid = (int)blockIdx.x;
  const int swz = (bid & 7) * 32 + (bid >> 3);
  const int b = swz >> 6;
  const int n0 = (swz & 63) << 6;
  const int nw = n0 + (w << 4);

  const bf16x8 qfrag =
      *(const bf16x8*)(qT + ((size_t)(b << 12) + nw + lo) * 32 + hi * 8);
  const unsigned short* kTb = kT + ((size_t)(b << 12)) * 32;
  const unsigned short* Fb = Fbf + ((size_t)b << 20);  // b*256*4096

  f32x4 oacc[16];
#pragma unroll
  for (int i = 0; i < 16; ++i) oacc[i] = (f32x4){0.f, 0.f, 0.f, 0.f};
  float m2[4] = {-INFINITY, -INFINITY, -INFINITY, -INFINITY};
  float lr[4] = {0.f, 0.f, 0.f, 0.f};

  const int c0 = tid >> 3;   // staging: row c0(+32p), 16B chunk ch
  const int ch = tid & 7;

  for (int mt = 0; mt < 64; ++mt) {
    {  // stage V tile: Vt[c][m] = Fbf[b][c][mt*64+m]
      const unsigned short* src = Fb + (size_t)c0 * 4096 + (mt << 6) + (ch << 3);
#pragma unroll
      for (int pp = 0; pp < 8; ++pp) {
        bf16x8 v = *(const bf16x8*)(src + (size_t)(pp * 32) * 4096);
        *(bf16x8*)(&Vt[c0 + pp * 32][ch << 3]) = v;
      }
    }
    __syncthreads();

    // S tile [16 rows x 64 cols], log2 domain (q pre-scaled by log2e)
    f32x4 s[4];
#pragma unroll
    for (int mf = 0; mf < 4; ++mf) {
      bf16x8 kf = *(const bf16x8*)(kTb +
          ((size_t)((mt << 6) + (mf << 4) + lo)) * 32 + hi * 8);
      f32x4 z = (f32x4){0.f, 0.f, 0.f, 0.f};
      s[mf] = __builtin_amdgcn_mfma_f32_16x16x32_bf16(qfrag, kf, z, 0, 0, 0);
    }

    // online softmax: rows = 4*hi + r, cols = lane&15 (+16*mf)
    float scale[4];
#pragma unroll
    for (int r = 0; r < 4; ++r) {
      float t = fmaxf(fmaxf(s[0][r], s[1][r]), fmaxf(s[2][r], s[3][r]));
      t = fmaxf(t, __shfl_xor(t, 1));
      t = fmaxf(t, __shfl_xor(t, 2));
      t = fmaxf(t, __shfl_xor(t, 4));
      t = fmaxf(t, __shfl_xor(t, 8));
      float mnew = fmaxf(m2[r], t);
      scale[r] = exp2f(m2[r] - mnew);   // exp2f(-inf)=0 on first tile
      m2[r] = mnew;
    }

    float rsum[4] = {0.f, 0.f, 0.f, 0.f};
#pragma unroll
    for (int mf = 0; mf < 4; ++mf) {
#pragma unroll
      for (int r = 0; r < 4; ++r) {
        float p = exp2f(s[mf][r] - m2[r]);
        rsum[r] += p;
        Pb[w][(hi << 2) + r][(mf << 4) + lo] = f2bf(p);
      }
    }
#pragma unroll
    for (int r = 0; r < 4; ++r) {
      float t = rsum[r];
      t += __shfl_xor(t, 1);
      t += __shfl_xor(t, 2);
      t += __shfl_xor(t, 4);
      t += __shfl_xor(t, 8);
      lr[r] = lr[r] * scale[r] + t;
    }
#pragma unroll
    for (int cs = 0; cs < 16; ++cs) {
#pragma unroll
      for (int r = 0; r < 4; ++r) oacc[cs][r] *= scale[r];
    }

    // PV: O[16 x 256] += P[16 x 64] @ V[64 x 256]
#pragma unroll
    for (int ms = 0; ms < 2; ++ms) {
      bf16x8 pf = *(const bf16x8*)(&Pb[w][lo][(ms << 5) + (hi << 3)]);
#pragma unroll
      for (int cs = 0; cs < 16; ++cs) {
        bf16x8 vf = *(const bf16x8*)(&Vt[(cs << 4) + lo][(ms << 5) + (hi << 3)]);
        oacc[cs] = __builtin_amdgcn_mfma_f32_16x16x32_bf16(pf, vf, oacc[cs], 0, 0, 0);
      }
    }
    __syncthreads();
  }

  // epilogue: out = F + O / l
  float inv[4];
#pragma unroll
  for (int r = 0; r < 4; ++r) inv[r] = 1.f / lr[r];
#pragma unroll
  for (int cs = 0; cs < 16; ++cs) {
#pragma unroll
    for (int r = 0; r < 4; ++r) {
      size_t idx = ((size_t)(b * 256) + (cs << 4) + lo) * 4096 + nw + (hi << 2) + r;
      out[idx] = F[idx] + oacc[cs][r] * inv[r];
    }
  }
}

extern "C" void kernel_launch(void* const* d_in, const int* in_sizes, int n_in,
                              void* d_out, int out_size, void* d_ws, size_t ws_size,
                              hipStream_t stream) {
  const float* F   = (const float*)d_in[0];
  const float* w1a = (const float*)d_in[1];
  const float* b1a = (const float*)d_in[2];
  const float* w1b = (const float*)d_in[3];
  const float* b1b = (const float*)d_in[4];
  const float* w2a = (const float*)d_in[5];
  const float* b2a = (const float*)d_in[6];
  const float* w2b = (const float*)d_in[7];
  const float* b2b = (const float*)d_in[8];
  float* out = (float*)d_out;

  char* ws = (char*)d_ws;
  float* w1aT = (float*)(ws);                       //  32 KB
  float* w2aT = (float*)(ws + 32768);               //  32 KB
  unsigned short* Fbf = (unsigned short*)(ws + 65536);              // 8 MB
  unsigned short* qT  = (unsigned short*)(ws + 65536 + 8388608);    // 1 MB
  unsigned short* kT  = (unsigned short*)(ws + 65536 + 8388608 + 1048576); // 1 MB

  hipLaunchKernelGGL(k_wprep, dim3(32), dim3(256), 0, stream, w1a, w2a, w1aT, w2aT);
  hipLaunchKernelGGL(k_qk, dim3(128), dim3(256), 0, stream,
                     F, w1aT, b1a, w1b, b1b, w2aT, b2a, w2b, b2b, Fbf, qT, kT);
  hipLaunchKernelGGL(k_attn, dim3(256), dim3(256), 0, stream, qT, kT, Fbf, F, out);
}